// Round 1
// baseline (86.785 us; speedup 1.0000x reference)
//
#include <hip/hip_runtime.h>
#include <math.h>

#define N 8
#define C 128
#define L 1024
#define K 100
#define TEMP 0.5f
#define EPS 1e-8f
#define NT (N * L)
#define ROWS 16   // c-rows per gemm_gather block; LDS dot tile = ROWS*L*4 = 64 KB

typedef _Float16 half8 __attribute__((ext_vector_type(8)));
typedef float f32x4 __attribute__((ext_vector_type(4)));

// Transpose+fp16-convert+fp32-row-norm-partials (unchanged from previous round).
// dst[n][l][ch] = (fp16) src[(n*C+ch)*slen + off + l]
// pdst[(n*L+l)*2 + c0/64] = partial sum of src^2 over this block's 64 channels
// blockIdx.z: 0-7 -> z slab n, 8-15 -> c slab n (skip col 0)
__global__ void __launch_bounds__(512)
transpose_both(const float* __restrict__ z, const float* __restrict__ c,
               _Float16* __restrict__ z_h, _Float16* __restrict__ c_h,
               float* __restrict__ zp, float* __restrict__ cp) {
    __shared__ float tile[64][65];
    __shared__ float part[8][64];
    const int which = blockIdx.z >> 3;
    const int n = blockIdx.z & 7;
    const float* src = which ? c : z;
    _Float16* dst = which ? c_h : z_h;
    float* pdst = which ? cp : zp;
    const int slen = which ? (L + 1) : L;
    const int off = which;
    const int l0 = blockIdx.x * 64;
    const int c0 = blockIdx.y * 64;
    const int tx = threadIdx.x;   // 0..63
    const int ty = threadIdx.y;   // 0..7
#pragma unroll
    for (int i = 0; i < 8; i++) {
        int chn = c0 + ty + i * 8;
        tile[ty + i * 8][tx] = src[((size_t)(n * C + chn)) * slen + off + l0 + tx];
    }
    __syncthreads();
#pragma unroll
    for (int i = 0; i < 8; i++) {
        int l = l0 + ty + i * 8;
        dst[((size_t)n * L + l) * C + c0 + tx] = (_Float16)tile[tx][ty + i * 8];
    }
    float p = 0.f;
#pragma unroll
    for (int i = 0; i < 8; i++) { float v = tile[ty * 8 + i][tx]; p += v * v; }
    part[ty][tx] = p;
    __syncthreads();
    if (ty == 0) {
        float sm = 0.f;
#pragma unroll
        for (int i = 0; i < 8; i++) sm += part[i][tx];
        pdst[(((size_t)n << 10) + l0 + tx) * 2 + (c0 >> 6)] = sm;
    }
}

// Dense MFMA GEMM (c_seq x z_seq^T, K=128) for 16 c-rows x all 1024 z-rows,
// dot tile parked in LDS, then gather of the 101 needed columns per row.
// Replaces the per-(n,t)-wave random-gather dot kernel (L1 line-request bound).
//
// MFMA 16x16x32_f16 operand mapping (m89/m92-verified):
//   arg0 (A): lane = r + 16*g holds A[r][8g..8g+7]     (A row-major, 16x128)
//   arg1 (B): lane = c + 16*g holds B^T[c][8g..8g+7]   (z_seq row-major = B^T)
//   D:        lane = c + 16*g, reg r holds D[4g+r][c]
__global__ void __launch_bounds__(512)
gemm_gather(const _Float16* __restrict__ zh, const _Float16* __restrict__ ch,
            const int* __restrict__ neg_inds,
            const float* __restrict__ zp, const float* __restrict__ cp,
            const float* __restrict__ z_orig, const float* __restrict__ c_orig,
            float* __restrict__ out) {
    __shared__ float dotL[ROWS * L];          // 64 KB -> 2 blocks/CU
    const int tid  = threadIdx.x;
    const int lane = tid & 63;
    const int w    = tid >> 6;                // wave 0..7, owns cols [w*128, w*128+128)
    const int n    = blockIdx.x >> 6;         // 64 blocks per n
    const int t0   = (blockIdx.x & 63) * ROWS;

    const int r16 = lane & 15;                // A-row / B-col within 16-tile
    const int kg  = lane >> 4;                // k-group 0..3 (8 halves each)

    const _Float16* Abase = ch + ((size_t)(n * L + t0)) * C;
    const _Float16* Bbase = zh + ((size_t)(n * L)) * C;

    // A fragments for all 4 K-steps stay in registers (16 VGPRs).
    half8 a[4];
#pragma unroll
    for (int ks = 0; ks < 4; ks++)
        a[ks] = *(const half8*)(Abase + (size_t)r16 * C + ks * 32 + kg * 8);

    f32x4 acc[8];
#pragma unroll
    for (int i = 0; i < 8; i++)
#pragma unroll
        for (int r = 0; r < 4; r++) acc[i][r] = 0.f;

    const int c0w = w << 7;
    // ks outer, nt inner: 8 independent MFMA chains per ks -> good ILP;
    // each B line of the z slab is fetched exactly once per block (L2-resident).
#pragma unroll
    for (int ks = 0; ks < 4; ks++) {
#pragma unroll
        for (int nt = 0; nt < 8; nt++) {
            const half8 b = *(const half8*)(Bbase
                + (size_t)(c0w + nt * 16 + r16) * C + ks * 32 + kg * 8);
            acc[nt] = __builtin_amdgcn_mfma_f32_16x16x32_f16(a[ks], b, acc[nt], 0, 0, 0);
        }
    }

    // Park dot tile in LDS: row = kg*4+r, col = c0w + nt*16 + r16.
#pragma unroll
    for (int nt = 0; nt < 8; nt++)
#pragma unroll
        for (int r = 0; r < 4; r++)
            dotL[(kg * 4 + r) * L + c0w + nt * 16 + r16] = acc[nt][r];

    __syncthreads();

    // Gather phase: 32 threads per c-row, each handles ~3-4 of the 101 targets.
    const int row = tid >> 5;                 // 0..15
    const int sub = tid & 31;                 // 0..31
    const int t   = t0 + row;
    const int ntg = (n << 10) + t;
    const float2 cpv = ((const float2*)cp)[ntg];
    const float cn = cpv.x + cpv.y;                           // fp32 ||c||^2
    const float rs_c = 2.0f * rsqrtf(fmaxf(cn, EPS * EPS));   // 1/(TEMP*sqrt(cn))
    const int* ni = neg_inds + (size_t)ntg * K;
    const float2* zp2 = (const float2*)zp + ((size_t)n << 10);
    float* orow = out + (size_t)ntg * (K + 1);

    for (int kk = sub; kk <= K; kk += 32) {
        const int col = (kk == 0) ? t : ni[kk - 1];
        const float dot = dotL[row * L + col];
        const float2 tv = zp2[col];
        const float tn = tv.x + tv.y;                         // fp32 ||z_col||^2
        float logit = dot * rs_c * rsqrtf(fmaxf(tn, EPS * EPS));
        if (kk > 0) {
            const float ds = cn - 2.f * dot + tn;             // ~0 iff c == z_col
            if (ds < 0.05f * cn) {                            // rare: exact fp32 recheck
                bool eq = true;
                for (int q = 0; q < C; q++) {
                    float cv = c_orig[((size_t)(n * C + q)) * (L + 1) + t + 1];
                    float zv = z_orig[((size_t)(n * C + q)) * L + col];
                    eq = eq && (cv == zv);
                }
                if (eq) logit = -INFINITY;
            }
        }
        orow[kk] = logit;
    }
}

extern "C" void kernel_launch(void* const* d_in, const int* in_sizes, int n_in,
                              void* d_out, int out_size, void* d_ws, size_t ws_size,
                              hipStream_t stream) {
    const float* z   = (const float*)d_in[0];   // (N, C, L)
    const float* c   = (const float*)d_in[1];   // (N, C, L+1)
    const int*   neg = (const int*)d_in[2];     // (N, L, K)
    float* out = (float*)d_out;                 // (N*L, K+1)

    _Float16* z_h = (_Float16*)d_ws;            // (N, L, C) fp16, 2 MB
    _Float16* c_h = z_h + (size_t)NT * C;       // (N, L, C) fp16, 2 MB
    float* zp = (float*)(c_h + (size_t)NT * C); // (N*L, 2) fp32 norm partials
    float* cp = zp + (size_t)NT * 2;            // (N*L, 2) fp32 norm partials

    transpose_both<<<dim3(L / 64, C / 64, 16), dim3(64, 8), 0, stream>>>(z, c, z_h, c_h, zp, cp);
    gemm_gather<<<dim3(N * (L / ROWS)), 512, 0, stream>>>(z_h, c_h, neg, zp, cp, z, c, out);
}

// Round 2
// 77.144 us; speedup vs baseline: 1.1250x; 1.1250x over previous
//
#include <hip/hip_runtime.h>
#include <math.h>

#define N 8
#define C 128
#define L 1024
#define K 100
#define TEMP 0.5f
#define EPS 1e-8f
#define NT (N * L)

typedef _Float16 half8 __attribute__((ext_vector_type(8)));
typedef float f32x4 __attribute__((ext_vector_type(4)));

// Fragment layout (half8 units): idx = ((n*64 + tile)*4 + ks)*64 + (r16 + 16*kg)
// holds element (l = tile*16 + r16, ch = ks*32 + kg*8 + e) in slot e.
// This IS the mfma_f32_16x16x32_f16 A/B operand order: lane r16+16*kg reads
// its own half8 with a fully-coalesced 1-KB wave load (no 16-way segment split).

// Transpose + fp16 convert into fragment layout + fp32 row-norm partials.
// blockIdx.z: 0-7 -> z slab n, 8-15 -> c slab n (skip col 0)
__global__ void __launch_bounds__(512)
transpose_frag(const float* __restrict__ z, const float* __restrict__ c,
               half8* __restrict__ zf, half8* __restrict__ cf,
               float* __restrict__ zp, float* __restrict__ cp) {
    __shared__ float tile[64][65];
    __shared__ float part[8][64];
    const int which = blockIdx.z >> 3;
    const int n = blockIdx.z & 7;
    const float* src = which ? c : z;
    half8* dst = which ? cf : zf;
    float* pdst = which ? cp : zp;
    const int slen = which ? (L + 1) : L;
    const int off = which;
    const int l0 = blockIdx.x * 64;
    const int c0 = blockIdx.y * 64;
    const int tx = threadIdx.x;   // 0..63  (local l)
    const int ty = threadIdx.y;   // 0..7   (8-channel chunk)
#pragma unroll
    for (int i = 0; i < 8; i++) {
        int chn = c0 + ty + i * 8;
        tile[ty + i * 8][tx] = src[((size_t)(n * C + chn)) * slen + off + l0 + tx];
    }
    __syncthreads();
    // thread (tx,ty): l = l0+tx, channels c0+ty*8 .. +7 -> one half8 fragment store
    float p = 0.f;
    half8 hv;
#pragma unroll
    for (int q = 0; q < 8; q++) {
        float v = tile[ty * 8 + q][tx];   // bank = (tx + 65*(ty*8+q))%32: 2/bank, free
        p += v * v;
        hv[q] = (_Float16)v;
    }
    const int l = l0 + tx;
    const int ch = c0 + ty * 8;
    const int ks = ch >> 5, kg = (ch >> 3) & 3;
    dst[(((size_t)(n * 64 + (l >> 4)) * 4 + ks) << 6) + (l & 15) + (kg << 4)] = hv;
    part[ty][tx] = p;   // partial ||.||^2 over this thread's 8 channels
    __syncthreads();
    if (ty == 0) {
        float sm = 0.f;
#pragma unroll
        for (int i = 0; i < 8; i++) sm += part[i][tx];
        pdst[(((size_t)n << 10) + l0 + tx) * 2 + (c0 >> 6)] = sm;
    }
}

// Dense MFMA GEMM (16 c-rows x 1024 z-rows, K=128) with all operand loads
// fully coalesced from the fragment layout; dot tile parked in LDS
// (2-way-swizzled, free); norms staged in LDS; then gather of 101 cols/row.
__global__ void __launch_bounds__(512)
gemm_gather(const half8* __restrict__ zf, const half8* __restrict__ cf,
            const int* __restrict__ neg_inds,
            const float* __restrict__ zp, const float* __restrict__ cp,
            const float* __restrict__ z_orig, const float* __restrict__ c_orig,
            float* __restrict__ out) {
    __shared__ float dotL[16 * L];        // 64 KB, col-swizzled by ^(2*row)
    __shared__ float2 zpl[L];             // 8 KB staged z norm-partials
    const int tid  = threadIdx.x;
    const int lane = tid & 63;
    const int w    = tid >> 6;            // wave 0..7, owns col-tiles 8w..8w+7
    const int n    = blockIdx.x >> 6;
    const int tA   = blockIdx.x & 63;     // c-row tile: rows [tA*16, tA*16+16)

    // stage z norm partials (coalesced, L2-resident 8 KB)
    const float2* zp2 = (const float2*)zp + ((size_t)n << 10);
    for (int i = tid; i < L; i += 512) zpl[i] = zp2[i];

    const size_t nbase = (size_t)n << 14;          // n * 64 tiles * 4 ks * 64 lanes
    half8 a[4];
#pragma unroll
    for (int ks = 0; ks < 4; ks++)                 // 4 coalesced 1-KB loads
        a[ks] = cf[nbase + (((tA << 2) + ks) << 6) + lane];

    f32x4 acc[8];
#pragma unroll
    for (int i = 0; i < 8; i++)
#pragma unroll
        for (int r = 0; r < 4; r++) acc[i][r] = 0.f;

#pragma unroll
    for (int ks = 0; ks < 4; ks++) {
#pragma unroll
        for (int nt = 0; nt < 8; nt++) {           // 32 coalesced 1-KB loads
            const half8 b = zf[nbase + ((size_t)(((w << 3) + nt) * 4 + ks) << 6) + lane];
            acc[nt] = __builtin_amdgcn_mfma_f32_16x16x32_f16(a[ks], b, acc[nt], 0, 0, 0);
        }
    }

    // Park dot tile: lane (r16,kg), reg r -> D[4*kg+r][tile*16+r16].
    // Swizzle col^(2*row): exactly 2 lanes/bank per ds_write (free, m136).
    const int r16 = lane & 15;
    const int kg  = lane >> 4;
#pragma unroll
    for (int nt = 0; nt < 8; nt++)
#pragma unroll
        for (int r = 0; r < 4; r++) {
            const int row = (kg << 2) + r;
            const int col = (((w << 3) + nt) << 4) + r16;
            dotL[(row << 10) + (col ^ (row << 1))] = acc[nt][r];
        }
    __syncthreads();

    // Gather phase: 32 threads per c-row, 101 targets per row, all LDS-side.
    const int row = tid >> 5;             // 0..15
    const int sub = tid & 31;
    const int t   = (tA << 4) + row;
    const int ntg = (n << 10) + t;
    const float2 cpv = ((const float2*)cp)[ntg];
    const float cn = cpv.x + cpv.y;                           // fp32 ||c||^2
    const float rs_c = 2.0f * rsqrtf(fmaxf(cn, EPS * EPS));   // 1/(TEMP*sqrt(cn))
    const int* ni = neg_inds + (size_t)ntg * K;
    float* orow = out + (size_t)ntg * (K + 1);

    for (int kk = sub; kk <= K; kk += 32) {
        const int col = (kk == 0) ? t : ni[kk - 1];
        const float dot = dotL[(row << 10) + (col ^ (row << 1))];
        const float2 tv = zpl[col];
        const float tn = tv.x + tv.y;                         // fp32 ||z_col||^2
        float logit = dot * rs_c * rsqrtf(fmaxf(tn, EPS * EPS));
        if (kk > 0) {
            const float ds = cn - 2.f * dot + tn;             // ~0 iff c == z_col
            if (ds < 0.05f * cn) {                            // rare: exact fp32 recheck
                bool eq = true;
                for (int q = 0; q < C; q++) {
                    float cv = c_orig[((size_t)(n * C + q)) * (L + 1) + t + 1];
                    float zv = z_orig[((size_t)(n * C + q)) * L + col];
                    eq = eq && (cv == zv);
                }
                if (eq) logit = -INFINITY;
            }
        }
        orow[kk] = logit;
    }
}

extern "C" void kernel_launch(void* const* d_in, const int* in_sizes, int n_in,
                              void* d_out, int out_size, void* d_ws, size_t ws_size,
                              hipStream_t stream) {
    const float* z   = (const float*)d_in[0];   // (N, C, L)
    const float* c   = (const float*)d_in[1];   // (N, C, L+1)
    const int*   neg = (const int*)d_in[2];     // (N, L, K)
    float* out = (float*)d_out;                 // (N*L, K+1)

    half8* zf = (half8*)d_ws;                   // fragment-layout z, 2 MB
    half8* cf = zf + (size_t)N * 16384;         // fragment-layout c, 2 MB
    float* zp = (float*)(cf + (size_t)N * 16384);  // (N*L, 2) fp32 norm partials
    float* cp = zp + (size_t)NT * 2;            // (N*L, 2) fp32 norm partials

    transpose_frag<<<dim3(L / 64, C / 64, 16), dim3(64, 8), 0, stream>>>(z, c, zf, cf, zp, cp);
    gemm_gather<<<dim3(N * (L / 16)), 512, 0, stream>>>(zf, cf, neg, zp, cp, z, c, out);
}

// Round 3
// 76.276 us; speedup vs baseline: 1.1378x; 1.0114x over previous
//
#include <hip/hip_runtime.h>
#include <math.h>

#define N 8
#define C 128
#define L 1024
#define K 100
#define TEMP 0.5f
#define EPS 1e-8f
#define NT (N * L)
#define ROWS 32   // c-rows per gemm_gather block; fp16 dot tile = 32*1024*2 = 64 KB

typedef _Float16 half8 __attribute__((ext_vector_type(8)));
typedef float f32x4 __attribute__((ext_vector_type(4)));

// Fragment layout (half8 units): idx = ((n*64 + tile)*4 + ks)*64 + (r16 + 16*kg)
// holds element (l = tile*16 + r16, ch = ks*32 + kg*8 + e) in slot e.
// This IS the mfma_f32_16x16x32_f16 A/B operand order: lane r16+16*kg reads
// its own half8 with a fully-coalesced 1-KB wave load.

// Transpose + fp16 convert into fragment layout + fp32 row-norm partials.
// blockIdx.z: 0-7 -> z slab n, 8-15 -> c slab n (skip col 0)
__global__ void __launch_bounds__(512)
transpose_frag(const float* __restrict__ z, const float* __restrict__ c,
               half8* __restrict__ zf, half8* __restrict__ cf,
               float* __restrict__ zp, float* __restrict__ cp) {
    __shared__ float tile[64][65];
    __shared__ float part[8][64];
    const int which = blockIdx.z >> 3;
    const int n = blockIdx.z & 7;
    const float* src = which ? c : z;
    half8* dst = which ? cf : zf;
    float* pdst = which ? cp : zp;
    const int slen = which ? (L + 1) : L;
    const int off = which;
    const int l0 = blockIdx.x * 64;
    const int c0 = blockIdx.y * 64;
    const int tx = threadIdx.x;   // 0..63  (local l)
    const int ty = threadIdx.y;   // 0..7   (8-channel chunk)
#pragma unroll
    for (int i = 0; i < 8; i++) {
        int chn = c0 + ty + i * 8;
        tile[ty + i * 8][tx] = src[((size_t)(n * C + chn)) * slen + off + l0 + tx];
    }
    __syncthreads();
    // thread (tx,ty): l = l0+tx, channels c0+ty*8 .. +7 -> one half8 fragment store
    float p = 0.f;
    half8 hv;
#pragma unroll
    for (int q = 0; q < 8; q++) {
        float v = tile[ty * 8 + q][tx];   // 2 lanes/bank: free (m136)
        p += v * v;
        hv[q] = (_Float16)v;
    }
    const int l = l0 + tx;
    const int ch = c0 + ty * 8;
    const int ks = ch >> 5, kg = (ch >> 3) & 3;
    dst[(((size_t)(n * 64 + (l >> 4)) * 4 + ks) << 6) + (l & 15) + (kg << 4)] = hv;
    part[ty][tx] = p;   // partial ||.||^2 over this thread's 8 channels
    __syncthreads();
    if (ty == 0) {
        float sm = 0.f;
#pragma unroll
        for (int i = 0; i < 8; i++) sm += part[i][tx];
        pdst[(((size_t)n << 10) + l0 + tx) * 2 + (c0 >> 6)] = sm;
    }
}

// Dense MFMA GEMM: 32 c-rows x 1024 z-rows, K=128. Each B fragment feeds TWO
// MFMAs (two A row-tiles) -> half the slab re-read traffic of ROWS=16.
// Dot tile parked in LDS as fp16 (64 KB); z-norms staged in LDS; gather of
// 101 cols/row is LDS+coalesced-global only.
__global__ void __launch_bounds__(512, 2)
gemm_gather(const half8* __restrict__ zf, const half8* __restrict__ cf,
            const int* __restrict__ neg_inds,
            const float* __restrict__ zp, const float* __restrict__ cp,
            const float* __restrict__ z_orig, const float* __restrict__ c_orig,
            float* __restrict__ out) {
    __shared__ _Float16 dotH[ROWS * L];   // 64 KB fp16 dot tile
    __shared__ float2 zpl[L];             // 8 KB staged z norm-partials
    const int tid  = threadIdx.x;
    const int lane = tid & 63;
    const int w    = tid >> 6;            // wave 0..7, owns cols [w*128, w*128+128)
    const int n    = blockIdx.x >> 5;     // 32 blocks per n
    const int tA   = blockIdx.x & 31;     // c-row tile: rows [tA*32, tA*32+32)

    // stage z norm partials (coalesced, L2-resident 8 KB)
    const float2* zp2 = (const float2*)zp + ((size_t)n << 10);
    for (int i = tid; i < L; i += 512) zpl[i] = zp2[i];

    const size_t nbase = (size_t)n << 14;          // n * 64 tiles * 4 ks * 64 lanes
    half8 a[2][4];
#pragma unroll
    for (int at = 0; at < 2; at++)
#pragma unroll
        for (int ks = 0; ks < 4; ks++)             // 8 coalesced 1-KB loads
            a[at][ks] = cf[nbase + ((((tA << 1) + at) * 4 + ks) << 6) + lane];

    f32x4 acc[2][8];
#pragma unroll
    for (int at = 0; at < 2; at++)
#pragma unroll
        for (int i = 0; i < 8; i++)
#pragma unroll
            for (int r = 0; r < 4; r++) acc[at][i][r] = 0.f;

#pragma unroll
    for (int ks = 0; ks < 4; ks++) {
        half8 b[8];
#pragma unroll
        for (int nt = 0; nt < 8; nt++)             // 8 coalesced 1-KB loads
            b[nt] = zf[nbase + ((size_t)(((w << 3) + nt) * 4 + ks) << 6) + lane];
#pragma unroll
        for (int nt = 0; nt < 8; nt++)
            acc[0][nt] = __builtin_amdgcn_mfma_f32_16x16x32_f16(a[0][ks], b[nt], acc[0][nt], 0, 0, 0);
#pragma unroll
        for (int nt = 0; nt < 8; nt++)
            acc[1][nt] = __builtin_amdgcn_mfma_f32_16x16x32_f16(a[1][ks], b[nt], acc[1][nt], 0, 0, 0);
    }

    // Park dot tile: lane (r16,kg), reg r of acc[at][nt] -> D[at*16+4*kg+r][w*128+nt*16+r16].
    // fp16 scalar stores; total LDS write volume is tiny vs load phase.
    const int r16 = lane & 15;
    const int kg  = lane >> 4;
#pragma unroll
    for (int at = 0; at < 2; at++)
#pragma unroll
        for (int nt = 0; nt < 8; nt++)
#pragma unroll
            for (int r = 0; r < 4; r++)
                dotH[((at << 4) + (kg << 2) + r) * L + (w << 7) + (nt << 4) + r16]
                    = (_Float16)acc[at][nt][r];
    __syncthreads();

    // Gather phase: 16 threads per c-row, 101 targets per row.
    const int row = tid >> 4;             // 0..31
    const int sub = tid & 15;
    const int t   = (tA << 5) + row;
    const int ntg = (n << 10) + t;
    const float2 cpv = ((const float2*)cp)[ntg];
    const float cn = cpv.x + cpv.y;                           // fp32 ||c||^2
    const float rs_c = 2.0f * rsqrtf(fmaxf(cn, EPS * EPS));   // 1/(TEMP*sqrt(cn))
    const int* ni = neg_inds + (size_t)ntg * K;
    float* orow = out + (size_t)ntg * (K + 1);

    for (int kk = sub; kk <= K; kk += 16) {
        const int col = (kk == 0) ? t : ni[kk - 1];
        const float dot = (float)dotH[row * L + col];
        const float2 tv = zpl[col];
        const float tn = tv.x + tv.y;                         // fp32 ||z_col||^2
        float logit = dot * rs_c * rsqrtf(fmaxf(tn, EPS * EPS));
        if (kk > 0) {
            const float ds = cn - 2.f * dot + tn;             // ~0 iff c == z_col
            if (ds < 0.05f * cn) {                            // rare: exact fp32 recheck
                bool eq = true;
                for (int q = 0; q < C; q++) {
                    float cv = c_orig[((size_t)(n * C + q)) * (L + 1) + t + 1];
                    float zv = z_orig[((size_t)(n * C + q)) * L + col];
                    eq = eq && (cv == zv);
                }
                if (eq) logit = -INFINITY;
            }
        }
        orow[kk] = logit;
    }
}

extern "C" void kernel_launch(void* const* d_in, const int* in_sizes, int n_in,
                              void* d_out, int out_size, void* d_ws, size_t ws_size,
                              hipStream_t stream) {
    const float* z   = (const float*)d_in[0];   // (N, C, L)
    const float* c   = (const float*)d_in[1];   // (N, C, L+1)
    const int*   neg = (const int*)d_in[2];     // (N, L, K)
    float* out = (float*)d_out;                 // (N*L, K+1)

    half8* zf = (half8*)d_ws;                   // fragment-layout z, 2 MB
    half8* cf = zf + (size_t)N * 16384;         // fragment-layout c, 2 MB
    float* zp = (float*)(cf + (size_t)N * 16384);  // (N*L, 2) fp32 norm partials
    float* cp = zp + (size_t)NT * 2;            // (N*L, 2) fp32 norm partials

    transpose_frag<<<dim3(L / 64, C / 64, 16), dim3(64, 8), 0, stream>>>(z, c, zf, cf, zp, cp);
    gemm_gather<<<dim3(N * (L / ROWS)), 512, 0, stream>>>(zf, cf, neg, zp, cp, z, c, out);
}

// Round 5
// 74.685 us; speedup vs baseline: 1.1620x; 1.0213x over previous
//
#include <hip/hip_runtime.h>
#include <math.h>

#define N 8
#define C 128
#define L 1024
#define K 100
#define TEMP 0.5f
#define EPS 1e-8f
#define NT (N * L)
#define ROWS 32   // c-rows per gemm_gather block; fp16 dot tile = 32*1024*2 = 64 KB

typedef _Float16 half8 __attribute__((ext_vector_type(8)));
typedef float f32x4 __attribute__((ext_vector_type(4)));

// Fragment layout (half8 units): idx = ((n*64 + tile)*4 + ks)*64 + (r16 + 16*kg)
// holds element (l = tile*16 + r16, ch = ks*32 + kg*8 + e) in slot e.
// This IS the mfma_f32_16x16x32_f16 A/B operand order: lane r16+16*kg reads
// its own half8 with a fully-coalesced 1-KB wave load.

// Transpose + fp16 convert into fragment layout + fp32 row-norm partials.
// blockIdx.z: 0-7 -> z slab n, 8-15 -> c slab n (skip col 0)
__global__ void __launch_bounds__(512)
transpose_frag(const float* __restrict__ z, const float* __restrict__ c,
               half8* __restrict__ zf, half8* __restrict__ cf,
               float* __restrict__ zp, float* __restrict__ cp) {
    __shared__ float tile[64][65];
    __shared__ float part[8][64];
    const int which = blockIdx.z >> 3;
    const int n = blockIdx.z & 7;
    const float* src = which ? c : z;
    half8* dst = which ? cf : zf;
    float* pdst = which ? cp : zp;
    const int slen = which ? (L + 1) : L;
    const int off = which;
    const int l0 = blockIdx.x * 64;
    const int c0 = blockIdx.y * 64;
    const int tx = threadIdx.x;   // 0..63  (local l)
    const int ty = threadIdx.y;   // 0..7   (8-channel chunk)
#pragma unroll
    for (int i = 0; i < 8; i++) {
        int chn = c0 + ty + i * 8;
        tile[ty + i * 8][tx] = src[((size_t)(n * C + chn)) * slen + off + l0 + tx];
    }
    __syncthreads();
    // thread (tx,ty): l = l0+tx, channels c0+ty*8 .. +7 -> one half8 fragment store
    float p = 0.f;
    half8 hv;
#pragma unroll
    for (int q = 0; q < 8; q++) {
        float v = tile[ty * 8 + q][tx];   // 2 lanes/bank: free (m136)
        p += v * v;
        hv[q] = (_Float16)v;
    }
    const int l = l0 + tx;
    const int ch = c0 + ty * 8;
    const int ks = ch >> 5, kg = (ch >> 3) & 3;
    dst[(((size_t)(n * 64 + (l >> 4)) * 4 + ks) << 6) + (l & 15) + (kg << 4)] = hv;
    part[ty][tx] = p;   // partial ||.||^2 over this thread's 8 channels
    __syncthreads();
    if (ty == 0) {
        float sm = 0.f;
#pragma unroll
        for (int i = 0; i < 8; i++) sm += part[i][tx];
        pdst[(((size_t)n << 10) + l0 + tx) * 2 + (c0 >> 6)] = sm;
    }
}

// Dense MFMA GEMM: 32 c-rows x 1024 z-rows, K=128, then fully-LDS gather of
// 101 cols/row. ALL global traffic is flat-coalesced: neg_inds slab and out
// slab for 32 consecutive rows are contiguous, staged through LDS.
__global__ void __launch_bounds__(512, 2)
gemm_gather(const half8* __restrict__ zf, const half8* __restrict__ cf,
            const int* __restrict__ neg_inds,
            const float* __restrict__ zp, const float* __restrict__ cp,
            const float* __restrict__ z_orig, const float* __restrict__ c_orig,
            float* __restrict__ out) {
    __shared__ _Float16 dotH[ROWS * L];     // 64 KB fp16 dot tile (kg-swizzled)
    __shared__ float ztn[L];                // 4 KB  ||z_col||^2
    __shared__ float ztr[L];                // 4 KB  rsqrt(max(tn, eps^2))
    __shared__ int   nil[ROWS * K];         // 12.8 KB staged neg_inds slab
    __shared__ float outF[ROWS * (K + 1)];  // 12.9 KB staged output slab
    const int tid  = threadIdx.x;
    const int lane = tid & 63;
    const int w    = tid >> 6;            // wave 0..7, owns cols [w*128, w*128+128)
    const int n    = blockIdx.x >> 5;     // 32 blocks per n
    const int tA   = blockIdx.x & 31;     // c-row tile: rows [tA*32, tA*32+32)
    const int ntg0 = (n << 10) + (tA << 5);

    // --- coalesced staging (issued early; latency hides under the MFMA loop) ---
    const float2* zp2 = (const float2*)zp + ((size_t)n << 10);
    for (int i = tid; i < L; i += 512) {
        float2 tv = zp2[i];
        float tn = tv.x + tv.y;
        ztn[i] = tn;
        ztr[i] = rsqrtf(fmaxf(tn, EPS * EPS));
    }
    const int* nb = neg_inds + (size_t)ntg0 * K;
    for (int i = tid; i < ROWS * K; i += 512) nil[i] = nb[i];

    // --- GEMM ---
    const size_t nbase = (size_t)n << 14;          // n * 64 tiles * 4 ks * 64 lanes
    half8 a[2][4];
#pragma unroll
    for (int at = 0; at < 2; at++)
#pragma unroll
        for (int ks = 0; ks < 4; ks++)             // 8 coalesced 1-KB loads
            a[at][ks] = cf[nbase + ((((tA << 1) + at) * 4 + ks) << 6) + lane];

    f32x4 acc[2][8];
#pragma unroll
    for (int at = 0; at < 2; at++)
#pragma unroll
        for (int i = 0; i < 8; i++)
#pragma unroll
            for (int r = 0; r < 4; r++) acc[at][i][r] = 0.f;

#pragma unroll
    for (int ks = 0; ks < 4; ks++) {
        half8 b[8];
#pragma unroll
        for (int nt = 0; nt < 8; nt++)             // 8 coalesced 1-KB loads
            b[nt] = zf[nbase + ((size_t)(((w << 3) + nt) * 4 + ks) << 6) + lane];
#pragma unroll
        for (int nt = 0; nt < 8; nt++)
            acc[0][nt] = __builtin_amdgcn_mfma_f32_16x16x32_f16(a[0][ks], b[nt], acc[0][nt], 0, 0, 0);
#pragma unroll
        for (int nt = 0; nt < 8; nt++)
            acc[1][nt] = __builtin_amdgcn_mfma_f32_16x16x32_f16(a[1][ks], b[nt], acc[1][nt], 0, 0, 0);
    }

    // Park dot tile: lane (r16,kg), reg r of acc[at][nt] ->
    // D[at*16+4*kg+r][w*128+nt*16+r16], column XOR-swizzled by kg so the 64
    // lanes of each b16 store hit 32 distinct banks (2 lanes/dword: free).
    const int r16 = lane & 15;
    const int kg  = lane >> 4;
#pragma unroll
    for (int at = 0; at < 2; at++)
#pragma unroll
        for (int nt = 0; nt < 8; nt++)
#pragma unroll
            for (int r = 0; r < 4; r++) {
                const int row = (at << 4) + (kg << 2) + r;
                const int col = (w << 7) + (nt << 4) + r16;
                dotH[row * L + (col ^ (kg << 4))] = (_Float16)acc[at][nt][r];
            }
    __syncthreads();

    // --- gather phase: 16 threads per c-row, contiguous kk ranges ---
    const int row = tid >> 4;             // 0..31
    const int sub = tid & 15;             // 0..15
    const int t   = (tA << 5) + row;
    const int ksw = ((row >> 2) & 3) << 4;   // kg-swizzle for this row
    const float2 cpv = ((const float2*)cp)[ntg0 + row];
    const float cn = cpv.x + cpv.y;                           // fp32 ||c||^2
    const float rs_c = 2.0f * rsqrtf(fmaxf(cn, EPS * EPS));   // 1/(TEMP*sqrt(cn))

#pragma unroll
    for (int j = 0; j < 7; j++) {
        const int kk = sub * 7 + j;       // stride-7 across lanes: conflict-light
        if (kk <= K) {
            const int col = (kk == 0) ? t : nil[row * K + kk - 1];
            const float dot = (float)dotH[row * L + (col ^ ksw)];
            const float tn = ztn[col];
            float logit = dot * rs_c * ztr[col];
            if (kk > 0) {
                const float ds = cn - 2.f * dot + tn;         // ~0 iff c == z_col
                if (ds < 0.05f * cn) {                        // rare: exact recheck
                    bool eq = true;
                    for (int q = 0; q < C; q++) {
                        float cv = c_orig[((size_t)(n * C + q)) * (L + 1) + t + 1];
                        float zv = z_orig[((size_t)(n * C + q)) * L + col];
                        eq = eq && (cv == zv);
                    }
                    if (eq) logit = -INFINITY;
                }
            }
            outF[row * (K + 1) + kk] = logit;
        }
    }
    __syncthreads();

    // --- flat coalesced writeback of the contiguous 32x101 output slab ---
    float* ob = out + (size_t)ntg0 * (K + 1);
    for (int i = tid; i < ROWS * (K + 1); i += 512) ob[i] = outF[i];
}

extern "C" void kernel_launch(void* const* d_in, const int* in_sizes, int n_in,
                              void* d_out, int out_size, void* d_ws, size_t ws_size,
                              hipStream_t stream) {
    const float* z   = (const float*)d_in[0];   // (N, C, L)
    const float* c   = (const float*)d_in[1];   // (N, C, L+1)
    const int*   neg = (const int*)d_in[2];     // (N, L, K)
    float* out = (float*)d_out;                 // (N*L, K+1)

    half8* zf = (half8*)d_ws;                   // fragment-layout z, 2 MB
    half8* cf = zf + (size_t)N * 16384;         // fragment-layout c, 2 MB
    float* zp = (float*)(cf + (size_t)N * 16384);  // (N*L, 2) fp32 norm partials
    float* cp = zp + (size_t)NT * 2;            // (N*L, 2) fp32 norm partials

    transpose_frag<<<dim3(L / 64, C / 64, 16), dim3(64, 8), 0, stream>>>(z, c, zf, cf, zp, cp);
    gemm_gather<<<dim3(N * (L / ROWS)), 512, 0, stream>>>(zf, cf, neg, zp, cp, z, c, out);
}

// Round 6
// 73.810 us; speedup vs baseline: 1.1758x; 1.0119x over previous
//
#include <hip/hip_runtime.h>
#include <math.h>

#define N 8
#define C 128
#define L 1024
#define K 100
#define TEMP 0.5f
#define EPS 1e-8f
#define NT (N * L)
#define ROWS 32   // c-rows per gemm_gather block; fp16 dot tile = 32*1024*2 = 64 KB

typedef _Float16 half8 __attribute__((ext_vector_type(8)));
typedef float f32x4 __attribute__((ext_vector_type(4)));

// Fragment layout (half8 units): idx = ((n*64 + tile)*4 + ks)*64 + (r16 + 16*kg)
// holds element (l = tile*16 + r16, ch = ks*32 + kg*8 + e) in slot e.
// This IS the mfma_f32_16x16x32_f16 A/B operand order: lane r16+16*kg reads
// its own half8 with a fully-coalesced 1-KB wave load.
//
// XCD pinning (this round's single change): HW round-robins workgroups across
// the 8 XCDs by dispatch index. Decoding n = blockIdx.x & 7 pins ALL blocks
// that touch slab n onto XCD n, so the 256-KB z-slab is pulled from L3 once
// and shared by the other 31 blocks out of the XCD-private 4-MB L2.

// Transpose + fp16 convert into fragment layout + fp32 row-norm partials.
// 1-D grid, 512 blocks: d&7 = n, (d>>3)&1 = which (0:z, 1:c), rest = tile coords.
__global__ void __launch_bounds__(512)
transpose_frag(const float* __restrict__ z, const float* __restrict__ c,
               half8* __restrict__ zf, half8* __restrict__ cf,
               float* __restrict__ zp, float* __restrict__ cp) {
    __shared__ float tile[64][65];
    __shared__ float part[8][64];
    const int d = blockIdx.x;
    const int n = d & 7;
    const int rest = d >> 3;              // 0..63
    const int which = rest & 1;
    const int c0 = ((rest >> 1) & 1) * 64;
    const int l0 = (rest >> 2) * 64;      // 0..15 -> *64
    const float* src = which ? c : z;
    half8* dst = which ? cf : zf;
    float* pdst = which ? cp : zp;
    const int slen = which ? (L + 1) : L;
    const int off = which;
    const int tx = threadIdx.x;   // 0..63  (local l)
    const int ty = threadIdx.y;   // 0..7   (8-channel chunk)
#pragma unroll
    for (int i = 0; i < 8; i++) {
        int chn = c0 + ty + i * 8;
        tile[ty + i * 8][tx] = src[((size_t)(n * C + chn)) * slen + off + l0 + tx];
    }
    __syncthreads();
    // thread (tx,ty): l = l0+tx, channels c0+ty*8 .. +7 -> one half8 fragment store
    float p = 0.f;
    half8 hv;
#pragma unroll
    for (int q = 0; q < 8; q++) {
        float v = tile[ty * 8 + q][tx];   // 2 lanes/bank: free (m136)
        p += v * v;
        hv[q] = (_Float16)v;
    }
    const int l = l0 + tx;
    const int ch = c0 + ty * 8;
    const int ks = ch >> 5, kg = (ch >> 3) & 3;
    dst[(((size_t)(n * 64 + (l >> 4)) * 4 + ks) << 6) + (l & 15) + (kg << 4)] = hv;
    part[ty][tx] = p;   // partial ||.||^2 over this thread's 8 channels
    __syncthreads();
    if (ty == 0) {
        float sm = 0.f;
#pragma unroll
        for (int i = 0; i < 8; i++) sm += part[i][tx];
        pdst[(((size_t)n << 10) + l0 + tx) * 2 + (c0 >> 6)] = sm;
    }
}

// Dense MFMA GEMM: 32 c-rows x 1024 z-rows, K=128, then fully-LDS gather of
// 101 cols/row. All global traffic flat-coalesced; slab reads L2-local via
// XCD pinning (n = blockIdx.x & 7).
__global__ void __launch_bounds__(512, 2)
gemm_gather(const half8* __restrict__ zf, const half8* __restrict__ cf,
            const int* __restrict__ neg_inds,
            const float* __restrict__ zp, const float* __restrict__ cp,
            const float* __restrict__ z_orig, const float* __restrict__ c_orig,
            float* __restrict__ out) {
    __shared__ _Float16 dotH[ROWS * L];     // 64 KB fp16 dot tile (kg-swizzled)
    __shared__ float ztn[L];                // 4 KB  ||z_col||^2
    __shared__ float ztr[L];                // 4 KB  rsqrt(max(tn, eps^2))
    __shared__ int   nil[ROWS * K];         // 12.8 KB staged neg_inds slab
    __shared__ float outF[ROWS * (K + 1)];  // 12.9 KB staged output slab
    const int tid  = threadIdx.x;
    const int lane = tid & 63;
    const int w    = tid >> 6;            // wave 0..7, owns cols [w*128, w*128+128)
    const int n    = blockIdx.x & 7;      // XCD-pinned: all blocks of slab n -> XCD n
    const int tA   = blockIdx.x >> 3;     // c-row tile: rows [tA*32, tA*32+32)
    const int ntg0 = (n << 10) + (tA << 5);

    // --- coalesced staging (issued early; latency hides under the MFMA loop) ---
    const float2* zp2 = (const float2*)zp + ((size_t)n << 10);
    for (int i = tid; i < L; i += 512) {
        float2 tv = zp2[i];
        float tn = tv.x + tv.y;
        ztn[i] = tn;
        ztr[i] = rsqrtf(fmaxf(tn, EPS * EPS));
    }
    const int* nb = neg_inds + (size_t)ntg0 * K;
    for (int i = tid; i < ROWS * K; i += 512) nil[i] = nb[i];

    // --- GEMM ---
    const size_t nbase = (size_t)n << 14;          // n * 64 tiles * 4 ks * 64 lanes
    half8 a[2][4];
#pragma unroll
    for (int at = 0; at < 2; at++)
#pragma unroll
        for (int ks = 0; ks < 4; ks++)             // 8 coalesced 1-KB loads
            a[at][ks] = cf[nbase + ((((tA << 1) + at) * 4 + ks) << 6) + lane];

    f32x4 acc[2][8];
#pragma unroll
    for (int at = 0; at < 2; at++)
#pragma unroll
        for (int i = 0; i < 8; i++)
#pragma unroll
            for (int r = 0; r < 4; r++) acc[at][i][r] = 0.f;

#pragma unroll
    for (int ks = 0; ks < 4; ks++) {
        half8 b[8];
#pragma unroll
        for (int nt = 0; nt < 8; nt++)             // 8 coalesced 1-KB loads
            b[nt] = zf[nbase + ((size_t)(((w << 3) + nt) * 4 + ks) << 6) + lane];
#pragma unroll
        for (int nt = 0; nt < 8; nt++)
            acc[0][nt] = __builtin_amdgcn_mfma_f32_16x16x32_f16(a[0][ks], b[nt], acc[0][nt], 0, 0, 0);
#pragma unroll
        for (int nt = 0; nt < 8; nt++)
            acc[1][nt] = __builtin_amdgcn_mfma_f32_16x16x32_f16(a[1][ks], b[nt], acc[1][nt], 0, 0, 0);
    }

    // Park dot tile: lane (r16,kg), reg r of acc[at][nt] ->
    // D[at*16+4*kg+r][w*128+nt*16+r16], column XOR-swizzled by kg so the 64
    // lanes of each b16 store hit 32 distinct banks (2 lanes/dword: free).
    const int r16 = lane & 15;
    const int kg  = lane >> 4;
#pragma unroll
    for (int at = 0; at < 2; at++)
#pragma unroll
        for (int nt = 0; nt < 8; nt++)
#pragma unroll
            for (int r = 0; r < 4; r++) {
                const int row = (at << 4) + (kg << 2) + r;
                const int col = (w << 7) + (nt << 4) + r16;
                dotH[row * L + (col ^ (kg << 4))] = (_Float16)acc[at][nt][r];
            }
    __syncthreads();

    // --- gather phase: 16 threads per c-row, contiguous kk ranges ---
    const int row = tid >> 4;             // 0..31
    const int sub = tid & 15;             // 0..15
    const int t   = (tA << 5) + row;
    const int ksw = ((row >> 2) & 3) << 4;   // kg-swizzle for this row
    const float2 cpv = ((const float2*)cp)[ntg0 + row];
    const float cn = cpv.x + cpv.y;                           // fp32 ||c||^2
    const float rs_c = 2.0f * rsqrtf(fmaxf(cn, EPS * EPS));   // 1/(TEMP*sqrt(cn))

#pragma unroll
    for (int j = 0; j < 7; j++) {
        const int kk = sub * 7 + j;       // stride-7 across lanes: conflict-light
        if (kk <= K) {
            const int col = (kk == 0) ? t : nil[row * K + kk - 1];
            const float dot = (float)dotH[row * L + (col ^ ksw)];
            const float tn = ztn[col];
            float logit = dot * rs_c * ztr[col];
            if (kk > 0) {
                const float ds = cn - 2.f * dot + tn;         // ~0 iff c == z_col
                if (ds < 0.05f * cn) {                        // rare: exact recheck
                    bool eq = true;
                    for (int q = 0; q < C; q++) {
                        float cv = c_orig[((size_t)(n * C + q)) * (L + 1) + t + 1];
                        float zv = z_orig[((size_t)(n * C + q)) * L + col];
                        eq = eq && (cv == zv);
                    }
                    if (eq) logit = -INFINITY;
                }
            }
            outF[row * (K + 1) + kk] = logit;
        }
    }
    __syncthreads();

    // --- flat coalesced writeback of the contiguous 32x101 output slab ---
    float* ob = out + (size_t)ntg0 * (K + 1);
    for (int i = tid; i < ROWS * (K + 1); i += 512) ob[i] = outF[i];
}

extern "C" void kernel_launch(void* const* d_in, const int* in_sizes, int n_in,
                              void* d_out, int out_size, void* d_ws, size_t ws_size,
                              hipStream_t stream) {
    const float* z   = (const float*)d_in[0];   // (N, C, L)
    const float* c   = (const float*)d_in[1];   // (N, C, L+1)
    const int*   neg = (const int*)d_in[2];     // (N, L, K)
    float* out = (float*)d_out;                 // (N*L, K+1)

    half8* zf = (half8*)d_ws;                   // fragment-layout z, 2 MB
    half8* cf = zf + (size_t)N * 16384;         // fragment-layout c, 2 MB
    float* zp = (float*)(cf + (size_t)N * 16384);  // (N*L, 2) fp32 norm partials
    float* cp = zp + (size_t)NT * 2;            // (N*L, 2) fp32 norm partials

    transpose_frag<<<dim3(512), dim3(64, 8), 0, stream>>>(z, c, zf, cf, zp, cp);
    gemm_gather<<<dim3(N * (L / ROWS)), 512, 0, stream>>>(zf, cf, neg, zp, cp, z, c, out);
}